// Round 4
// baseline (583.715 us; speedup 1.0000x reference)
//
#include <hip/hip_runtime.h>
#include <cstdint>
#include <cstddef>

#define HH 12
#define DHD 64
#define BB 64
#define SS 512
#define DD 768
#define PP 256
#define N3 2304

typedef __attribute__((ext_vector_type(8))) short bf16x8_t;
typedef __attribute__((ext_vector_type(4))) float f32x4_t;

__constant__ float c_slopes[12] = {
  0.5f, 0.25f, 0.125f, 0.0625f, 0.03125f, 0.015625f, 0.0078125f, 0.00390625f,
  0.70710678118654752f, 0.35355339059327376f, 0.17677669529663688f, 0.08838834764831844f
};

__device__ __forceinline__ ushort f2bf(float f) {
  union { float f; unsigned u; } v; v.f = f;
  unsigned r = v.u + 0x7fffu + ((v.u >> 16) & 1u);  // RNE
  return (ushort)(r >> 16);
}
__device__ __forceinline__ float bf2f(ushort u) {
  union { unsigned u; float f; } v; v.u = ((unsigned)u) << 16;
  return v.f;
}
__device__ __forceinline__ void gload_lds16(const ushort* g, ushort* l) {
  __builtin_amdgcn_global_load_lds(
      (const __attribute__((address_space(1))) void*)g,
      (__attribute__((address_space(3))) void*)l, 16, 0, 0);
}

// ---------------- cast hidden_states fp32 -> bf16 ----------------
__global__ void cast_hs_kernel(const float* __restrict__ in, ushort* __restrict__ out) {
  int i = blockIdx.x * 256 + threadIdx.x;          // exactly 6291456 float4 groups
  float4 v = ((const float4*)in)[i];
  ushort4 o;
  o.x = f2bf(v.x); o.y = f2bf(v.y); o.z = f2bf(v.z); o.w = f2bf(v.w);
  ((ushort4*)out)[i] = o;
}

// ---------------- transpose + cast W (768x2304) -> Wt bf16 (2304x768) ----------------
__global__ void transpose_w_kernel(const float* __restrict__ W, ushort* __restrict__ Wt) {
  __shared__ float tile[32][33];
  int n0 = blockIdx.x * 32, k0 = blockIdx.y * 32;
  int tx = threadIdx.x & 31, ty = threadIdx.x >> 5;
  for (int r = ty; r < 32; r += 8) tile[r][tx] = W[(size_t)(k0 + r) * N3 + n0 + tx];
  __syncthreads();
  for (int r = ty; r < 32; r += 8) Wt[(size_t)(n0 + r) * DD + k0 + tx] = f2bf(tile[tx][r]);
}

// ---------------- GEMM (m97 structure + L2 swizzle): qkv = (A.W + bias) * mask ----------------
__global__ __launch_bounds__(256) void gemm_qkv_kernel(
    const ushort* __restrict__ A, const ushort* __restrict__ Wt,
    const float* __restrict__ bias, const int* __restrict__ mask,
    ushort* __restrict__ qkv) {
  __shared__ __align__(16) ushort As[128 * 32];
  __shared__ __align__(16) ushort Bs[128 * 32];
  // swizzle: 144 consecutive blocks = 8 m-blocks x 18 n-blocks (A-rows + full Wt ~5MB hot)
  const int bid = blockIdx.x;
  const int group = bid / 144, inner = bid % 144;
  const int bn = (inner % 18) * 128;
  const int bm = (group * 8 + inner / 18) * 128;
  const int tid = threadIdx.x;
  const int lane = tid & 63;
  const int wave = tid >> 6;
  const int wm = (wave & 1) * 64;
  const int wn = (wave >> 1) * 64;
  const int fr = lane & 15, quad = lane >> 4;
  const int srow = wave * 32 + (lane >> 2);
  const int scol = (lane & 3) * 8;
  const ushort* Ag0 = A  + (size_t)(bm + srow) * DD + scol;
  const ushort* Ag1 = Ag0 + 16 * DD;
  const ushort* Bg0 = Wt + (size_t)(bn + srow) * DD + scol;
  const ushort* Bg1 = Bg0 + 16 * DD;
  ushort* AsW0 = As + (wave * 2 + 0) * 512;
  ushort* AsW1 = As + (wave * 2 + 1) * 512;
  ushort* BsW0 = Bs + (wave * 2 + 0) * 512;
  ushort* BsW1 = Bs + (wave * 2 + 1) * 512;

  f32x4_t acc[4][4];
  for (int i = 0; i < 4; i++)
    for (int j = 0; j < 4; j++) acc[i][j] = (f32x4_t){0.f, 0.f, 0.f, 0.f};

  for (int k0 = 0; k0 < DD; k0 += 32) {
    gload_lds16(Ag0 + k0, AsW0);
    gload_lds16(Ag1 + k0, AsW1);
    gload_lds16(Bg0 + k0, BsW0);
    gload_lds16(Bg1 + k0, BsW1);
    __syncthreads();
    bf16x8_t af[4], bfv[4];
    for (int mt = 0; mt < 4; mt++) af[mt]  = *(const bf16x8_t*)&As[(wm + mt*16 + fr) * 32 + quad*8];
    for (int nt = 0; nt < 4; nt++) bfv[nt] = *(const bf16x8_t*)&Bs[(wn + nt*16 + fr) * 32 + quad*8];
    for (int mt = 0; mt < 4; mt++)
      for (int nt = 0; nt < 4; nt++)
        acc[mt][nt] = __builtin_amdgcn_mfma_f32_16x16x32_bf16(af[mt], bfv[nt], acc[mt][nt], 0, 0, 0);
    __syncthreads();
  }
  for (int mt = 0; mt < 4; mt++) {
    const int mbase = bm + wm + mt*16 + quad*4;
    for (int r = 0; r < 4; r++) {
      const int m = mbase + r;
      const float mval = (float)mask[m];
      for (int nt = 0; nt < 4; nt++) {
        const int n = bn + wn + nt*16 + fr;
        float v = (acc[mt][nt][r] + bias[n]) * mval;
        qkv[(size_t)m * N3 + n] = f2bf(v);
      }
    }
  }
}

// ---------------- transpose V third of qkv -> Vt[b][h][d][s] ----------------
__global__ void transpose_v_kernel(const ushort* __restrict__ qkv, ushort* __restrict__ Vt) {
  __shared__ ushort tile[64][72];
  const int t = blockIdx.x, h = blockIdx.y, b = blockIdx.z;   // t = s-tile (64 rows)
  const int r = threadIdx.x >> 3;          // 0..31
  const int c8 = (threadIdx.x & 7) * 8;
  const ushort* src = qkv + (size_t)(b*512 + t*64) * N3 + 1536 + h*64;
  *(float4*)&tile[r][c8]    = *(const float4*)(src + (size_t)r * N3 + c8);
  *(float4*)&tile[r+32][c8] = *(const float4*)(src + (size_t)(r+32) * N3 + c8);
  __syncthreads();
  const int d = threadIdx.x >> 3;          // 0..31
  const int s8 = (threadIdx.x & 7) * 8;
  ushort* dst = Vt + (size_t)(b*12 + h) * 64 * 512 + t*64 + s8;
  ushort tmp[8];
  for (int j = 0; j < 8; j++) tmp[j] = tile[s8 + j][d];
  *(float4*)(dst + (size_t)d * 512) = *(float4*)tmp;
  for (int j = 0; j < 8; j++) tmp[j] = tile[s8 + j][d + 32];
  *(float4*)(dst + (size_t)(d + 32) * 512) = *(float4*)tmp;
}

// ---------------- pool: residual_query + new_mask ----------------
__global__ void pool_kernel(const ushort* __restrict__ qkv, const int* __restrict__ mask,
                            float* __restrict__ out) {
  int idx = blockIdx.x * 256 + threadIdx.x;       // 64*256*192 total
  int d4 = idx % 192;
  int bp = idx / 192;
  int b = bp >> 8, p = bp & 255;
  int m0 = mask[b*512 + 2*p], m1 = mask[b*512 + 2*p + 1];
  int ms = m0 + m1;
  float inv = 1.0f / (float)(ms < 1 ? 1 : ms);
  const ushort* r0 = qkv + (size_t)(b*512 + 2*p) * N3 + d4*4;
  ushort4 x0 = *(const ushort4*)r0;
  ushort4 x1 = *(const ushort4*)(r0 + N3);
  float4 y;
  y.x = (bf2f(x0.x) + bf2f(x1.x)) * inv;
  y.y = (bf2f(x0.y) + bf2f(x1.y)) * inv;
  y.z = (bf2f(x0.z) + bf2f(x1.z)) * inv;
  y.w = (bf2f(x0.w) + bf2f(x1.w)) * inv;
  *(float4*)(out + 12599296 + (size_t)bp * 768 + d4*4) = y;    // residual_query
  if (d4 == 0) out[12582912 + bp] = (ms > 0) ? 1.0f : 0.0f;    // new_mask
}

// ---------------- attention: per (p-tile 16, h, b); direct-global fragments ----------------
__global__ __launch_bounds__(256) void attn_kernel(
    const ushort* __restrict__ qkv, const ushort* __restrict__ Vt,
    const int* __restrict__ mask, const float* __restrict__ nmask,
    float* __restrict__ outA) {
  __shared__ __align__(16) float sc[16][520];      // scores; rows later aliased as bf16 P
  const int pt = blockIdx.x, h = blockIdx.y, b = blockIdx.z;
  const int pbase = pt * 16;
  const int tid = threadIdx.x, wave = tid >> 6, lane = tid & 63;
  const int fr = lane & 15, quad = lane >> 4;

  // ---- Q fragments pooled on the fly (A-layout: m=fr, k=quad*8+j) ----
  const int p_lane = pbase + fr;
  const int qm0 = mask[b*512 + 2*p_lane], qm1 = mask[b*512 + 2*p_lane + 1];
  const int qms = qm0 + qm1;
  const float qscale = 0.125f / (float)(qms < 1 ? 1 : qms);   // fold 1/sqrt(64)
  const ushort* qrow = qkv + (size_t)(b*512 + 2*p_lane) * N3 + h*64 + quad*8;
  bf16x8_t a0, a1;
  {
    bf16x8_t r0 = *(const bf16x8_t*)qrow;
    bf16x8_t r1 = *(const bf16x8_t*)(qrow + N3);
    bf16x8_t s0 = *(const bf16x8_t*)(qrow + 32);
    bf16x8_t s1 = *(const bf16x8_t*)(qrow + 32 + N3);
    for (int j = 0; j < 8; j++) {
      a0[j] = (short)f2bf((bf2f((ushort)r0[j]) + bf2f((ushort)r1[j])) * qscale);
      a1[j] = (short)f2bf((bf2f((ushort)s0[j]) + bf2f((ushort)s1[j])) * qscale);
    }
  }

  // ---- QK^T: wave covers s in [wave*128, wave*128+128); B-frags direct from global ----
  const ushort* Krow = qkv + (size_t)(b*512 + wave*128 + fr) * N3 + 768 + h*64 + quad*8;
  #pragma unroll
  for (int st = 0; st < 8; st++) {
    bf16x8_t b0 = *(const bf16x8_t*)(Krow + (size_t)st*16*N3);
    bf16x8_t b1 = *(const bf16x8_t*)(Krow + (size_t)st*16*N3 + 32);
    f32x4_t d = (f32x4_t){0.f, 0.f, 0.f, 0.f};
    d = __builtin_amdgcn_mfma_f32_16x16x32_bf16(a0, b0, d, 0, 0, 0);
    d = __builtin_amdgcn_mfma_f32_16x16x32_bf16(a1, b1, d, 0, 0, 0);
    for (int r = 0; r < 4; r++) sc[quad*4 + r][wave*128 + st*16 + fr] = d[r];
  }
  __syncthreads();

  // ---- softmax + bias (ALiBi + pair mask); P -> bf16 aliased over sc rows ----
  const float slope = c_slopes[h];
  int kvalid[8];
  for (int j = 0; j < 8; j++) kvalid[j] = mask[b*512 + lane + j*64];
  for (int i = 0; i < 4; i++) {
    int r = wave*4 + i;
    int p = pbase + r;
    bool rowv = nmask[b*256 + p] > 0.5f;
    float vals[8];
    float mx = -3.0e38f;
    for (int j = 0; j < 8; j++) {
      int s = lane + j*64;
      float v = sc[r][s];
      v += ((rowv && kvalid[j]) ? 0.0f : -10000.0f) - slope * fabsf((float)(s - p));
      vals[j] = v;
      mx = fmaxf(mx, v);
    }
    for (int off = 32; off > 0; off >>= 1) mx = fmaxf(mx, __shfl_xor(mx, off, 64));
    float sum = 0.f;
    for (int j = 0; j < 8; j++) { vals[j] = __expf(vals[j] - mx); sum += vals[j]; }
    for (int off = 32; off > 0; off >>= 1) sum += __shfl_xor(sum, off, 64);
    float inv = 1.0f / sum;
    ushort* prow = (ushort*)&sc[r][0];
    for (int j = 0; j < 8; j++) prow[lane + j*64] = f2bf(vals[j] * inv);
  }
  __syncthreads();

  // ---- P.V: wave covers d in [wave*16, wave*16+16); V B-frags direct from Vt ----
  const ushort* Vrow = Vt + ((size_t)(b*12 + h) * 64 + wave*16 + fr) * 512 + quad*8;
  const ushort* prow = (const ushort*)&sc[fr][0] + quad*8;
  f32x4_t acc = (f32x4_t){0.f, 0.f, 0.f, 0.f};
  #pragma unroll
  for (int ks = 0; ks < 16; ks++) {
    bf16x8_t bv = *(const bf16x8_t*)(Vrow + ks*32);
    bf16x8_t ap = *(const bf16x8_t*)(prow + ks*32);
    acc = __builtin_amdgcn_mfma_f32_16x16x32_bf16(ap, bv, acc, 0, 0, 0);
  }
  for (int r = 0; r < 4; r++) {
    int p = pbase + quad*4 + r;
    float nm = nmask[b*256 + p];
    outA[(size_t)(b*256 + p) * 768 + h*64 + wave*16 + fr] = acc[r] * nm;
  }
}

extern "C" void kernel_launch(void* const* d_in, const int* in_sizes, int n_in,
                              void* d_out, int out_size, void* d_ws, size_t ws_size,
                              hipStream_t stream) {
  const float* hs   = (const float*)d_in[0];
  const int*   mask = (const int*)d_in[1];
  const float* W    = (const float*)d_in[2];
  const float* bias = (const float*)d_in[3];
  float* out = (float*)d_out;
  char* ws = (char*)d_ws;
  // ws layout (bytes): qkv [0, 150994944) ; A [150994944, 201326592) ;
  //                    Wt [201326592, 204865536). Vt aliases A (A dead after GEMM).
  ushort* qkv = (ushort*)(ws);
  ushort* A   = (ushort*)(ws + 150994944);
  ushort* Wt  = (ushort*)(ws + 201326592);
  ushort* Vt  = (ushort*)(ws + 150994944);

  hipLaunchKernelGGL(cast_hs_kernel, dim3(24576), dim3(256), 0, stream, hs, A);
  hipLaunchKernelGGL(transpose_w_kernel, dim3(72, 24), dim3(256), 0, stream, W, Wt);
  hipLaunchKernelGGL(gemm_qkv_kernel, dim3(4608), dim3(256), 0, stream, A, Wt, bias, mask, qkv);
  hipLaunchKernelGGL(transpose_v_kernel, dim3(8, 12, 64), dim3(256), 0, stream, qkv, Vt);
  hipLaunchKernelGGL(pool_kernel, dim3(12288), dim3(256), 0, stream, qkv, mask, out);
  hipLaunchKernelGGL(attn_kernel, dim3(16, 12, 64), dim3(256), 0, stream,
                     qkv, Vt, mask, out + 12582912, out);
}

// Round 5
// 579.629 us; speedup vs baseline: 1.0070x; 1.0070x over previous
//
#include <hip/hip_runtime.h>
#include <cstdint>
#include <cstddef>

#define HH 12
#define DHD 64
#define BB 64
#define SS 512
#define DD 768
#define PP 256
#define N3 2304

typedef __attribute__((ext_vector_type(8))) short bf16x8_t;
typedef __attribute__((ext_vector_type(4))) float f32x4_t;

__constant__ float c_slopes[12] = {
  0.5f, 0.25f, 0.125f, 0.0625f, 0.03125f, 0.015625f, 0.0078125f, 0.00390625f,
  0.70710678118654752f, 0.35355339059327376f, 0.17677669529663688f, 0.08838834764831844f
};

__device__ __forceinline__ ushort f2bf(float f) {
  union { float f; unsigned u; } v; v.f = f;
  unsigned r = v.u + 0x7fffu + ((v.u >> 16) & 1u);  // RNE
  return (ushort)(r >> 16);
}
__device__ __forceinline__ float bf2f(ushort u) {
  union { unsigned u; float f; } v; v.u = ((unsigned)u) << 16;
  return v.f;
}
__device__ __forceinline__ void gload_lds16(const ushort* g, ushort* l) {
  __builtin_amdgcn_global_load_lds(
      (const __attribute__((address_space(1))) void*)g,
      (__attribute__((address_space(3))) void*)l, 16, 0, 0);
}

// ---------------- cast hidden_states fp32 -> bf16 ----------------
__global__ void cast_hs_kernel(const float* __restrict__ in, ushort* __restrict__ out) {
  int i = blockIdx.x * 256 + threadIdx.x;          // exactly 6291456 float4 groups
  float4 v = ((const float4*)in)[i];
  ushort4 o;
  o.x = f2bf(v.x); o.y = f2bf(v.y); o.z = f2bf(v.z); o.w = f2bf(v.w);
  ((ushort4*)out)[i] = o;
}

// ---------------- transpose + cast W (768x2304) -> Wt bf16 (2304x768) ----------------
__global__ void transpose_w_kernel(const float* __restrict__ W, ushort* __restrict__ Wt) {
  __shared__ float tile[32][33];
  int n0 = blockIdx.x * 32, k0 = blockIdx.y * 32;
  int tx = threadIdx.x & 31, ty = threadIdx.x >> 5;
  for (int r = ty; r < 32; r += 8) tile[r][tx] = W[(size_t)(k0 + r) * N3 + n0 + tx];
  __syncthreads();
  for (int r = ty; r < 32; r += 8) Wt[(size_t)(n0 + r) * DD + k0 + tx] = f2bf(tile[tx][r]);
}

// ---------------- GEMM (m97 structure + XCD-aware swizzle) ----------------
// xcd = bid % 8 (round-robin). All 18 n-blocks of one m-panel land on one XCD:
// bid = (M0/8)*144 + n*8 + (M0%8)  ->  A-panel (192 KB) stays hot in that XCD's L2.
__global__ __launch_bounds__(256) void gemm_qkv_kernel(
    const ushort* __restrict__ A, const ushort* __restrict__ Wt,
    const float* __restrict__ bias, const int* __restrict__ mask,
    ushort* __restrict__ qkv) {
  __shared__ __align__(16) ushort As[128 * 32];
  __shared__ __align__(16) ushort Bs[128 * 32];
  const int bid = blockIdx.x;
  const int c = bid & 7;
  const int t = bid >> 3;            // 0..575
  const int nb = t % 18;
  const int M0 = (t / 18) * 8 + c;   // 0..255
  const int bm = M0 * 128;
  const int bn = nb * 128;
  const int tid = threadIdx.x;
  const int lane = tid & 63;
  const int wave = tid >> 6;
  const int wm = (wave & 1) * 64;
  const int wn = (wave >> 1) * 64;
  const int fr = lane & 15, quad = lane >> 4;
  const int srow = wave * 32 + (lane >> 2);
  const int scol = (lane & 3) * 8;
  const ushort* Ag0 = A  + (size_t)(bm + srow) * DD + scol;
  const ushort* Ag1 = Ag0 + 16 * DD;
  const ushort* Bg0 = Wt + (size_t)(bn + srow) * DD + scol;
  const ushort* Bg1 = Bg0 + 16 * DD;
  ushort* AsW0 = As + (wave * 2 + 0) * 512;
  ushort* AsW1 = As + (wave * 2 + 1) * 512;
  ushort* BsW0 = Bs + (wave * 2 + 0) * 512;
  ushort* BsW1 = Bs + (wave * 2 + 1) * 512;

  f32x4_t acc[4][4];
  for (int i = 0; i < 4; i++)
    for (int j = 0; j < 4; j++) acc[i][j] = (f32x4_t){0.f, 0.f, 0.f, 0.f};

  for (int k0 = 0; k0 < DD; k0 += 32) {
    gload_lds16(Ag0 + k0, AsW0);
    gload_lds16(Ag1 + k0, AsW1);
    gload_lds16(Bg0 + k0, BsW0);
    gload_lds16(Bg1 + k0, BsW1);
    __syncthreads();
    bf16x8_t af[4], bfv[4];
    for (int mt = 0; mt < 4; mt++) af[mt]  = *(const bf16x8_t*)&As[(wm + mt*16 + fr) * 32 + quad*8];
    for (int nt = 0; nt < 4; nt++) bfv[nt] = *(const bf16x8_t*)&Bs[(wn + nt*16 + fr) * 32 + quad*8];
    for (int mt = 0; mt < 4; mt++)
      for (int nt = 0; nt < 4; nt++)
        acc[mt][nt] = __builtin_amdgcn_mfma_f32_16x16x32_bf16(af[mt], bfv[nt], acc[mt][nt], 0, 0, 0);
    __syncthreads();
  }
  for (int mt = 0; mt < 4; mt++) {
    const int mbase = bm + wm + mt*16 + quad*4;
    for (int r = 0; r < 4; r++) {
      const int m = mbase + r;
      const float mval = (float)mask[m];
      for (int nt = 0; nt < 4; nt++) {
        const int n = bn + wn + nt*16 + fr;
        float v = (acc[mt][nt][r] + bias[n]) * mval;
        qkv[(size_t)m * N3 + n] = f2bf(v);
      }
    }
  }
}

// ---------------- transpose V third of qkv -> Vt[b][h][d][s] ----------------
__global__ void transpose_v_kernel(const ushort* __restrict__ qkv, ushort* __restrict__ Vt) {
  __shared__ ushort tile[64][72];
  const int t = blockIdx.x, h = blockIdx.y, b = blockIdx.z;   // t = s-tile (64 rows)
  const int r = threadIdx.x >> 3;          // 0..31
  const int c8 = (threadIdx.x & 7) * 8;
  const ushort* src = qkv + (size_t)(b*512 + t*64) * N3 + 1536 + h*64;
  *(float4*)&tile[r][c8]    = *(const float4*)(src + (size_t)r * N3 + c8);
  *(float4*)&tile[r+32][c8] = *(const float4*)(src + (size_t)(r+32) * N3 + c8);
  __syncthreads();
  const int d = threadIdx.x >> 3;          // 0..31
  const int s8 = (threadIdx.x & 7) * 8;
  ushort* dst = Vt + (size_t)(b*12 + h) * 64 * 512 + t*64 + s8;
  ushort tmp[8];
  for (int j = 0; j < 8; j++) tmp[j] = tile[s8 + j][d];
  *(float4*)(dst + (size_t)d * 512) = *(float4*)tmp;
  for (int j = 0; j < 8; j++) tmp[j] = tile[s8 + j][d + 32];
  *(float4*)(dst + (size_t)(d + 32) * 512) = *(float4*)tmp;
}

// ---------------- pool: residual_query + new_mask ----------------
__global__ void pool_kernel(const ushort* __restrict__ qkv, const int* __restrict__ mask,
                            float* __restrict__ out) {
  int idx = blockIdx.x * 256 + threadIdx.x;       // 64*256*192 total
  int d4 = idx % 192;
  int bp = idx / 192;
  int b = bp >> 8, p = bp & 255;
  int m0 = mask[b*512 + 2*p], m1 = mask[b*512 + 2*p + 1];
  int ms = m0 + m1;
  float inv = 1.0f / (float)(ms < 1 ? 1 : ms);
  const ushort* r0 = qkv + (size_t)(b*512 + 2*p) * N3 + d4*4;
  ushort4 x0 = *(const ushort4*)r0;
  ushort4 x1 = *(const ushort4*)(r0 + N3);
  float4 y;
  y.x = (bf2f(x0.x) + bf2f(x1.x)) * inv;
  y.y = (bf2f(x0.y) + bf2f(x1.y)) * inv;
  y.z = (bf2f(x0.z) + bf2f(x1.z)) * inv;
  y.w = (bf2f(x0.w) + bf2f(x1.w)) * inv;
  *(float4*)(out + 12599296 + (size_t)bp * 768 + d4*4) = y;    // residual_query
  if (d4 == 0) out[12582912 + bp] = (ms > 0) ? 1.0f : 0.0f;    // new_mask
}

// ---------------- attention: XCD-aware 1D grid; direct-global fragments ----------------
// g = (h,b) group (0..767), pt = p-tile (0..15). All 16 pt of one g map to the
// same XCD: bid = (g/8)*128 + pt*8 + (g%8)  (xcd = bid%8 round-robin).
__global__ __launch_bounds__(256) void attn_kernel(
    const ushort* __restrict__ qkv, const ushort* __restrict__ Vt,
    const int* __restrict__ mask, const float* __restrict__ nmask,
    float* __restrict__ outA) {
  __shared__ __align__(16) float sc[16][520];      // scores; rows later aliased as bf16 P
  const int bid = blockIdx.x;
  const int cxcd = bid & 7;
  const int tt = bid >> 3;              // 0..1535
  const int pt = tt & 15;
  const int g = (tt >> 4) * 8 + cxcd;   // 0..767
  const int h = g % 12, b = g / 12;
  const int pbase = pt * 16;
  const int tid = threadIdx.x, wave = tid >> 6, lane = tid & 63;
  const int fr = lane & 15, quad = lane >> 4;

  // ---- Q fragments pooled on the fly (A-layout: m=fr, k=quad*8+j) ----
  const int p_lane = pbase + fr;
  const int qm0 = mask[b*512 + 2*p_lane], qm1 = mask[b*512 + 2*p_lane + 1];
  const int qms = qm0 + qm1;
  const float qscale = 0.125f / (float)(qms < 1 ? 1 : qms);   // fold 1/sqrt(64)
  const ushort* qrow = qkv + (size_t)(b*512 + 2*p_lane) * N3 + h*64 + quad*8;
  bf16x8_t a0, a1;
  {
    bf16x8_t r0 = *(const bf16x8_t*)qrow;
    bf16x8_t r1 = *(const bf16x8_t*)(qrow + N3);
    bf16x8_t s0 = *(const bf16x8_t*)(qrow + 32);
    bf16x8_t s1 = *(const bf16x8_t*)(qrow + 32 + N3);
    for (int j = 0; j < 8; j++) {
      a0[j] = (short)f2bf((bf2f((ushort)r0[j]) + bf2f((ushort)r1[j])) * qscale);
      a1[j] = (short)f2bf((bf2f((ushort)s0[j]) + bf2f((ushort)s1[j])) * qscale);
    }
  }

  // ---- QK^T: wave covers s in [wave*128, wave*128+128); B-frags direct from global ----
  const ushort* Krow = qkv + (size_t)(b*512 + wave*128 + fr) * N3 + 768 + h*64 + quad*8;
  #pragma unroll
  for (int st = 0; st < 8; st++) {
    bf16x8_t b0 = *(const bf16x8_t*)(Krow + (size_t)st*16*N3);
    bf16x8_t b1 = *(const bf16x8_t*)(Krow + (size_t)st*16*N3 + 32);
    f32x4_t d = (f32x4_t){0.f, 0.f, 0.f, 0.f};
    d = __builtin_amdgcn_mfma_f32_16x16x32_bf16(a0, b0, d, 0, 0, 0);
    d = __builtin_amdgcn_mfma_f32_16x16x32_bf16(a1, b1, d, 0, 0, 0);
    for (int r = 0; r < 4; r++) sc[quad*4 + r][wave*128 + st*16 + fr] = d[r];
  }
  __syncthreads();

  // ---- softmax + bias (ALiBi + pair mask); P -> bf16 aliased over sc rows ----
  const float slope = c_slopes[h];
  int kvalid[8];
  for (int j = 0; j < 8; j++) kvalid[j] = mask[b*512 + lane + j*64];
  for (int i = 0; i < 4; i++) {
    int r = wave*4 + i;
    int p = pbase + r;
    bool rowv = nmask[b*256 + p] > 0.5f;
    float vals[8];
    float mx = -3.0e38f;
    for (int j = 0; j < 8; j++) {
      int s = lane + j*64;
      float v = sc[r][s];
      v += ((rowv && kvalid[j]) ? 0.0f : -10000.0f) - slope * fabsf((float)(s - p));
      vals[j] = v;
      mx = fmaxf(mx, v);
    }
    for (int off = 32; off > 0; off >>= 1) mx = fmaxf(mx, __shfl_xor(mx, off, 64));
    float sum = 0.f;
    for (int j = 0; j < 8; j++) { vals[j] = __expf(vals[j] - mx); sum += vals[j]; }
    for (int off = 32; off > 0; off >>= 1) sum += __shfl_xor(sum, off, 64);
    float inv = 1.0f / sum;
    ushort* prow = (ushort*)&sc[r][0];
    for (int j = 0; j < 8; j++) prow[lane + j*64] = f2bf(vals[j] * inv);
  }
  __syncthreads();

  // ---- P.V: wave covers d in [wave*16, wave*16+16); V B-frags direct from Vt ----
  const ushort* Vrow = Vt + ((size_t)(b*12 + h) * 64 + wave*16 + fr) * 512 + quad*8;
  const ushort* prow = (const ushort*)&sc[fr][0] + quad*8;
  f32x4_t acc = (f32x4_t){0.f, 0.f, 0.f, 0.f};
  #pragma unroll
  for (int ks = 0; ks < 16; ks++) {
    bf16x8_t bv = *(const bf16x8_t*)(Vrow + ks*32);
    bf16x8_t ap = *(const bf16x8_t*)(prow + ks*32);
    acc = __builtin_amdgcn_mfma_f32_16x16x32_bf16(ap, bv, acc, 0, 0, 0);
  }
  for (int r = 0; r < 4; r++) {
    int p = pbase + quad*4 + r;
    float nm = nmask[b*256 + p];
    outA[(size_t)(b*256 + p) * 768 + h*64 + wave*16 + fr] = acc[r] * nm;
  }
}

extern "C" void kernel_launch(void* const* d_in, const int* in_sizes, int n_in,
                              void* d_out, int out_size, void* d_ws, size_t ws_size,
                              hipStream_t stream) {
  const float* hs   = (const float*)d_in[0];
  const int*   mask = (const int*)d_in[1];
  const float* W    = (const float*)d_in[2];
  const float* bias = (const float*)d_in[3];
  float* out = (float*)d_out;
  char* ws = (char*)d_ws;
  // ws layout (bytes): qkv [0, 150994944) ; A [150994944, 201326592) ;
  //                    Wt [201326592, 204865536). Vt aliases A (A dead after GEMM).
  ushort* qkv = (ushort*)(ws);
  ushort* A   = (ushort*)(ws + 150994944);
  ushort* Wt  = (ushort*)(ws + 201326592);
  ushort* Vt  = (ushort*)(ws + 150994944);

  hipLaunchKernelGGL(cast_hs_kernel, dim3(24576), dim3(256), 0, stream, hs, A);
  hipLaunchKernelGGL(transpose_w_kernel, dim3(72, 24), dim3(256), 0, stream, W, Wt);
  hipLaunchKernelGGL(gemm_qkv_kernel, dim3(4608), dim3(256), 0, stream, A, Wt, bias, mask, qkv);
  hipLaunchKernelGGL(transpose_v_kernel, dim3(8, 12, 64), dim3(256), 0, stream, qkv, Vt);
  hipLaunchKernelGGL(pool_kernel, dim3(12288), dim3(256), 0, stream, qkv, mask, out);
  hipLaunchKernelGGL(attn_kernel, dim3(12288), dim3(256), 0, stream,
                     qkv, Vt, mask, out + 12582912, out);
}